// Round 7
// baseline (453.420 us; speedup 1.0000x reference)
//
#include <hip/hip_runtime.h>
#include <math.h>

#define DIN 1024
#define DOUT 1024
#define NHEAD 16
#define HDIM 64
#define BATCH 2
#define TSEQ 2048
#define MROWS (BATCH * TSEQ) // 4096

typedef unsigned short u16;
typedef unsigned long long u64;
typedef __attribute__((ext_vector_type(8))) short short8;
typedef __attribute__((ext_vector_type(4))) float f32x4;
typedef __attribute__((ext_vector_type(4))) unsigned short us4;

// round-to-nearest-even split of fp32 into bf16 hi + bf16 lo (x ~= hi + lo)
__device__ __forceinline__ void f32_to_bf16pair(float x, u16& hi, u16& lo) {
  unsigned u = __float_as_uint(x);
  unsigned r = (u + 0x7fffu + ((u >> 16) & 1u)) & 0xffff0000u;
  hi = (u16)(r >> 16);
  float rem = x - __uint_as_float(r);
  unsigned u2 = __float_as_uint(rem);
  lo = (u16)((u2 + 0x7fffu + ((u2 >> 16) & 1u)) >> 16);
}

// async 16B global->LDS (dst = wave-uniform base, HW adds lane*16)
__device__ __forceinline__ void gld_lds16(const void* g, void* l) {
  __builtin_amdgcn_global_load_lds(
      (__attribute__((address_space(1))) void*)g,
      (__attribute__((address_space(3))) void*)l, 16, 0, 0);
}

// ===========================================================================
// mask_pack: int mask [B][T][T] -> bit mask [B][T][T/64] (u64, bit=lane key)
// one wave packs one (b, qrow) row: 32 coalesced loads + __ballot each.
// ===========================================================================
__global__ __launch_bounds__(256) void mask_pack(const int* __restrict__ mask,
                                                 u64* __restrict__ bits) {
  const int gw = blockIdx.x * 4 + (threadIdx.x >> 6); // 0..4095 = b*T + t
  const int lane = threadIdx.x & 63;
  const int* row = mask + (size_t)gw * TSEQ;
  u64* orow = bits + (size_t)gw * (TSEQ / 64);
#pragma unroll 4
  for (int kt = 0; kt < TSEQ / 64; ++kt) {
    int m = row[kt * 64 + lane];
    u64 b = __ballot(m != 0);
    if (lane == 0) orow[kt] = b;
  }
}

// ===========================================================================
// splitWt: fp32 W [K][N] -> bf16 hi/lo W^T [N][K] for 4 weights (blockIdx.z)
// ===========================================================================
__global__ __launch_bounds__(256) void splitWt(
    const float* __restrict__ W0, const float* __restrict__ W1,
    const float* __restrict__ W2, const float* __restrict__ W3,
    u16* __restrict__ H0, u16* __restrict__ L0, u16* __restrict__ H1,
    u16* __restrict__ L1, u16* __restrict__ H2, u16* __restrict__ L2,
    u16* __restrict__ H3, u16* __restrict__ L3) {
  const int z = blockIdx.z;
  const float* W = z == 0 ? W0 : z == 1 ? W1 : z == 2 ? W2 : W3;
  u16* H = z == 0 ? H0 : z == 1 ? H1 : z == 2 ? H2 : H3;
  u16* L = z == 0 ? L0 : z == 1 ? L1 : z == 2 ? L2 : L3;
  __shared__ float ts[64][68];
  const int tid = threadIdx.x;
  const int k0 = blockIdx.y * 64, n0 = blockIdx.x * 64;
  {
    const int kl = tid >> 2, nc = (tid & 3) * 16;
#pragma unroll
    for (int c = 0; c < 4; ++c)
      *(float4*)&ts[kl][nc + c * 4] =
          *(const float4*)&W[(size_t)(k0 + kl) * DOUT + n0 + nc + c * 4];
  }
  __syncthreads();
  const int nl = tid >> 2, kc = (tid & 3) * 16;
#pragma unroll
  for (int g = 0; g < 4; ++g) {
    us4 h4, l4;
#pragma unroll
    for (int j = 0; j < 4; ++j) {
      u16 hh, ll;
      f32_to_bf16pair(ts[kc + g * 4 + j][nl], hh, ll);
      h4[j] = hh;
      l4[j] = ll;
    }
    const size_t idx = (size_t)(n0 + nl) * DIN + k0 + kc + g * 4;
    *(us4*)&H[idx] = h4;
    *(us4*)&L[idx] = l4;
  }
}

// ===========================================================================
// QKV projection GEMM, fused fp32->split: A staged as RAW fp32 tiles
// (128x32 f32 = 16 KB, same LDS bytes as a hi|lo bf16 pair), split to
// bf16 hi/lo in-register at fragment-load time. B = pre-split W^T hi/lo.
// 3-pass Markidis MFMA. Tile 128x128, BK=32, 4 waves. XOR-swizzled rows.
// mode 0: out bf16 hi/lo (b,h,t,d);  mode 2: bf16 hi/lo (b,h,d,t).
// ===========================================================================
struct QkvPtrs {
  const float* Af;
  const u16* Bh;
  const u16* Bl;
  u16* Oh;
  u16* Ol;
  int mode;
};
struct QkvArgs {
  QkvPtrs p[3];
};

__global__ __launch_bounds__(256) void gemm_qkv(QkvArgs args) {
  const QkvPtrs P = args.p[blockIdx.z];
  __shared__ alignas(16) float Abuf[128 * 32]; // fp32 rows: 8 chunks of 16 B
  __shared__ alignas(16) u16 Bbuf[128 * 64];   // [32 hi | 32 lo] rows
  const int tid = threadIdx.x;
  const int w = tid >> 6, lane = tid & 63;
  const int lr = lane & 15, qd = lane >> 4;
  const int mw = w >> 1, nw = w & 1;
  const int n0 = blockIdx.x * 128, m0 = blockIdx.y * 128;

  const float* gA[4];
  const u16* gB[4];
  float* lA[4];
  u16* lB[4];
  {
    const int cl = lane & 7;
#pragma unroll
    for (int is = 0; is < 4; ++is) {
      const int row = is * 32 + w * 8 + (lane >> 3);
      const int cg = cl ^ (row & 7); // global chunk that lands at LDS slot cl
      gA[is] = P.Af + (size_t)(m0 + row) * DIN + cg * 4; // 4 f32 = 16 B
      gB[is] = (cg < 4 ? P.Bh : P.Bl) + (size_t)(n0 + row) * DIN + (cg & 3) * 8;
      lA[is] = Abuf + (size_t)(is * 32 + w * 8) * 32;
      lB[is] = Bbuf + (size_t)(is * 32 + w * 8) * 64;
    }
  }

  f32x4 acc[4][4] = {};

  for (int kt = 0; kt < 32; ++kt) {
    __syncthreads();
#pragma unroll
    for (int is = 0; is < 4; ++is) {
      gld_lds16(gA[is], lA[is]);
      gld_lds16(gB[is], lB[is]);
      gA[is] += 32; // 32 f32 per K-step
      gB[is] += 32; // 32 u16 per K-step
    }
    __syncthreads();

    // A fragments: read 8 f32, split to hi/lo short8 in-register
    short8 afh[4], afl[4];
#pragma unroll
    for (int t = 0; t < 4; ++t) {
      const int ra = mw * 64 + t * 16 + lr;
      const float* rp = &Abuf[ra * 32];
      f32x4 a0 = *(const f32x4*)&rp[(((2 * qd) ^ (ra & 7)) * 4)];
      f32x4 a1 = *(const f32x4*)&rp[(((2 * qd + 1) ^ (ra & 7)) * 4)];
#pragma unroll
      for (int j = 0; j < 4; ++j) {
        u16 hh, ll;
        f32_to_bf16pair(a0[j], hh, ll);
        afh[t][j] = (short)hh;
        afl[t][j] = (short)ll;
        f32_to_bf16pair(a1[j], hh, ll);
        afh[t][4 + j] = (short)hh;
        afl[t][4 + j] = (short)ll;
      }
    }
    short8 bfh[4], bfl[4];
#pragma unroll
    for (int t = 0; t < 4; ++t) {
      const int rb = nw * 64 + t * 16 + lr;
      bfh[t] = *(const short8*)&Bbuf[rb * 64 + ((qd ^ (rb & 7)) << 3)];
      bfl[t] = *(const short8*)&Bbuf[rb * 64 + (((qd + 4) ^ (rb & 7)) << 3)];
    }
#pragma unroll
    for (int mt = 0; mt < 4; ++mt)
#pragma unroll
      for (int nt = 0; nt < 4; ++nt) {
        acc[mt][nt] = __builtin_amdgcn_mfma_f32_16x16x32_bf16(
            afh[mt], bfh[nt], acc[mt][nt], 0, 0, 0);
        acc[mt][nt] = __builtin_amdgcn_mfma_f32_16x16x32_bf16(
            afh[mt], bfl[nt], acc[mt][nt], 0, 0, 0);
        acc[mt][nt] = __builtin_amdgcn_mfma_f32_16x16x32_bf16(
            afl[mt], bfh[nt], acc[mt][nt], 0, 0, 0);
      }
  }

#pragma unroll
  for (int mt = 0; mt < 4; ++mt)
#pragma unroll
    for (int nt = 0; nt < 4; ++nt)
#pragma unroll
      for (int r = 0; r < 4; ++r) {
        const float val = acc[mt][nt][r];
        const int gm = m0 + mw * 64 + mt * 16 + qd * 4 + r;
        const int gn = n0 + nw * 64 + nt * 16 + lr;
        u16 hh16, ll16;
        f32_to_bf16pair(val, hh16, ll16);
        const int bb = gm >> 11, t = gm & 2047;
        const int h = gn >> 6, d = gn & 63;
        size_t idx;
        if (P.mode == 0)
          idx = (((size_t)(bb * NHEAD + h) * TSEQ) + t) * HDIM + d;
        else
          idx = (((size_t)(bb * NHEAD + h) * HDIM) + d) * TSEQ + t;
        P.Oh[idx] = hh16;
        P.Ol[idx] = ll16;
      }
}

// ===========================================================================
// Out-projection GEMM, K-split x2 (blockIdx.z = K-half) -> partial fp32
// buffers C0/C1 (deterministic; summed by sumC). 512 blocks = 2/CU.
// ===========================================================================
__global__ __launch_bounds__(256) void gemm_out(
    const u16* __restrict__ Ah, const u16* __restrict__ Al,
    const u16* __restrict__ Bh, const u16* __restrict__ Bl,
    float* __restrict__ C0, float* __restrict__ C1) {
  float* Of = blockIdx.z == 0 ? C0 : C1;
  const int koff = blockIdx.z * 512; // u16 elements into each K-row
  __shared__ alignas(16) u16 Abuf[128 * 64];
  __shared__ alignas(16) u16 Bbuf[128 * 64];
  const int tid = threadIdx.x;
  const int w = tid >> 6, lane = tid & 63;
  const int lr = lane & 15, qd = lane >> 4;
  const int mw = w >> 1, nw = w & 1;
  const int n0 = blockIdx.x * 128, m0 = blockIdx.y * 128;

  const u16* gA[4];
  const u16* gB[4];
  u16* lA[4];
  u16* lB[4];
  {
    const int cl = lane & 7;
#pragma unroll
    for (int is = 0; is < 4; ++is) {
      const int row = is * 32 + w * 8 + (lane >> 3);
      const int cg = cl ^ (row & 7);
      gA[is] = (cg < 4 ? Ah : Al) + (size_t)(m0 + row) * DIN + (cg & 3) * 8 + koff;
      gB[is] = (cg < 4 ? Bh : Bl) + (size_t)(n0 + row) * DIN + (cg & 3) * 8 + koff;
      lA[is] = Abuf + (size_t)(is * 32 + w * 8) * 64;
      lB[is] = Bbuf + (size_t)(is * 32 + w * 8) * 64;
    }
  }

  f32x4 acc[4][4] = {};

  for (int kt = 0; kt < 16; ++kt) {
    __syncthreads();
#pragma unroll
    for (int is = 0; is < 4; ++is) {
      gld_lds16(gA[is], lA[is]);
      gld_lds16(gB[is], lB[is]);
      gA[is] += 32;
      gB[is] += 32;
    }
    __syncthreads();

    short8 af[4][2], bf[4][2];
#pragma unroll
    for (int t = 0; t < 4; ++t) {
      const int ra = mw * 64 + t * 16 + lr;
      af[t][0] = *(const short8*)&Abuf[ra * 64 + ((qd ^ (ra & 7)) << 3)];
      af[t][1] = *(const short8*)&Abuf[ra * 64 + (((qd + 4) ^ (ra & 7)) << 3)];
      const int rb = nw * 64 + t * 16 + lr;
      bf[t][0] = *(const short8*)&Bbuf[rb * 64 + ((qd ^ (rb & 7)) << 3)];
      bf[t][1] = *(const short8*)&Bbuf[rb * 64 + (((qd + 4) ^ (rb & 7)) << 3)];
    }
#pragma unroll
    for (int mt = 0; mt < 4; ++mt)
#pragma unroll
      for (int nt = 0; nt < 4; ++nt) {
        acc[mt][nt] = __builtin_amdgcn_mfma_f32_16x16x32_bf16(
            af[mt][0], bf[nt][0], acc[mt][nt], 0, 0, 0);
        acc[mt][nt] = __builtin_amdgcn_mfma_f32_16x16x32_bf16(
            af[mt][0], bf[nt][1], acc[mt][nt], 0, 0, 0);
        acc[mt][nt] = __builtin_amdgcn_mfma_f32_16x16x32_bf16(
            af[mt][1], bf[nt][0], acc[mt][nt], 0, 0, 0);
      }
  }

#pragma unroll
  for (int mt = 0; mt < 4; ++mt)
#pragma unroll
    for (int nt = 0; nt < 4; ++nt)
#pragma unroll
      for (int r = 0; r < 4; ++r) {
        const int gm = m0 + mw * 64 + mt * 16 + qd * 4 + r;
        const int gn = n0 + nw * 64 + nt * 16 + lr;
        Of[(size_t)gm * DOUT + gn] = acc[mt][nt][r];
      }
}

__global__ __launch_bounds__(256) void sumC(const float* __restrict__ A,
                                            const float* __restrict__ B,
                                            float* __restrict__ O) {
  const size_t i = ((size_t)blockIdx.x * 256 + threadIdx.x) * 4;
  float4 a = *(const float4*)&A[i];
  float4 b = *(const float4*)&B[i];
  *(float4*)&O[i] = make_float4(a.x + b.x, a.y + b.y, a.z + b.z, a.w + b.w);
}

// ===========================================================================
// MFMA flash attention, 64 q-rows per block (4 waves x 16 rows), 1024 blocks.
// XCD-aware remap; K/V staged via async global_load_lds (global-side XOR
// swizzle); mask read from the 1 MiB bit-pack (4 x 8B loads per iter).
// LDS 40 KB -> 4 blocks/CU. z written as bf16 hi/lo row-major.
// ===========================================================================
__global__ __launch_bounds__(256, 4) void attn64q(
    const u16* __restrict__ qh, const u16* __restrict__ ql,
    const u16* __restrict__ kh, const u16* __restrict__ kl,
    const u16* __restrict__ vh, const u16* __restrict__ vl,
    const u64* __restrict__ bits, u16* __restrict__ zh,
    u16* __restrict__ zl) {
  __shared__ alignas(16) u16 lds_k[2][64 * 64]; // [hi/lo][key][d]
  __shared__ alignas(16) u16 lds_v[2][64 * 64]; // [hi/lo][d][key]
  __shared__ alignas(16) u16 lds_p[4][16 * 64]; // [wave][q][key]
  const int tid = threadIdx.x;
  const int w = tid >> 6, lane = tid & 63;
  const int lr = lane & 15, qd = lane >> 4;
  const int L = blockIdx.x;
  const int bh = (L & 7) + 8 * ((L >> 3) & 3);
  const int qt0 = (L >> 5) * 64;
  const int bb = bh >> 4, hh = bh & 15;
  const int wq0 = qt0 + w * 16;
  const size_t bh_off = (size_t)bh * TSEQ * HDIM;

  short8 qf[2][2];
#pragma unroll
  for (int ks = 0; ks < 2; ++ks) {
    const size_t off = bh_off + (size_t)(wq0 + lr) * HDIM + ks * 32 + qd * 8;
    qf[ks][0] = *(const short8*)(qh + off);
    qf[ks][1] = *(const short8*)(ql + off);
  }

  f32x4 zacc[4] = {};
  float lsum[4] = {};

  const u16* ssrc = (w == 0 ? kh : w == 1 ? kl : w == 2 ? vh : vl) + bh_off;
  u16* sdst = (w < 2) ? &lds_k[w][0] : &lds_v[w - 2][0];
  const bool isk = (w < 2);
  const int srow = lane >> 3, scl = lane & 7;
  const u64* brow = bits + ((size_t)bb * TSEQ + wq0 + qd * 4) * (TSEQ / 64);

  for (int kt0 = 0; kt0 < TSEQ; kt0 += 64) {
    __syncthreads();
#pragma unroll
    for (int is = 0; is < 8; ++is) {
      const int row = is * 8 + srow;
      const int cg = scl ^ (row & 7);
      const u16* src = isk ? ssrc + (size_t)(kt0 + row) * HDIM + cg * 8
                           : ssrc + (size_t)row * TSEQ + kt0 + cg * 8;
      gld_lds16(src, sdst + is * 512);
    }
    __syncthreads();

    u64 bm[4];
#pragma unroll
    for (int r = 0; r < 4; ++r) bm[r] = brow[r * (TSEQ / 64) + (kt0 >> 6)];

    // S = Q K^T, 3-pass split
    f32x4 sacc[4] = {};
#pragma unroll
    for (int ks = 0; ks < 2; ++ks)
#pragma unroll
      for (int nt = 0; nt < 4; ++nt) {
        const int krow = nt * 16 + lr;
        const int chunk = (((ks * 4 + qd) ^ (krow & 7)) << 3);
        short8 bhf = *(const short8*)&lds_k[0][krow * 64 + chunk];
        short8 blf = *(const short8*)&lds_k[1][krow * 64 + chunk];
        sacc[nt] = __builtin_amdgcn_mfma_f32_16x16x32_bf16(qf[ks][0], bhf,
                                                           sacc[nt], 0, 0, 0);
        sacc[nt] = __builtin_amdgcn_mfma_f32_16x16x32_bf16(qf[ks][0], blf,
                                                           sacc[nt], 0, 0, 0);
        sacc[nt] = __builtin_amdgcn_mfma_f32_16x16x32_bf16(qf[ks][1], bhf,
                                                           sacc[nt], 0, 0, 0);
      }

    // p = exp(scale*s) or 0; quantize to bf16; accumulate l over quantized p
    u16* pw = &lds_p[w][0];
#pragma unroll
    for (int nt = 0; nt < 4; ++nt)
#pragma unroll
      for (int r = 0; r < 4; ++r) {
        float s = sacc[nt][r];
        const unsigned keep = (unsigned)(bm[r] >> (nt * 16 + lr)) & 1u;
        s = keep ? s * 0.125f : -1.0e9f;
        float p = __expf(s);
        unsigned u = (__float_as_uint(p) + 0x8000u) & 0xffff0000u;
        lsum[r] += __uint_as_float(u);
        const int prow = qd * 4 + r;
        const int pcol = nt * 16 + lr;
        pw[prow * 64 + ((((pcol >> 3) ^ (prow & 7)) << 3)) + (pcol & 7)] =
            (u16)(u >> 16);
      }

    // Z += P V (V hi/lo 2-pass)
#pragma unroll
    for (int ks = 0; ks < 2; ++ks) {
      const int chunkp = (((ks * 4 + qd) ^ (lr & 7)) << 3);
      short8 pf = *(const short8*)&pw[lr * 64 + chunkp];
#pragma unroll
      for (int nt = 0; nt < 4; ++nt) {
        const int vrow = nt * 16 + lr;
        const int chunk = (((ks * 4 + qd) ^ (vrow & 7)) << 3);
        short8 vhf = *(const short8*)&lds_v[0][vrow * 64 + chunk];
        short8 vlf = *(const short8*)&lds_v[1][vrow * 64 + chunk];
        zacc[nt] = __builtin_amdgcn_mfma_f32_16x16x32_bf16(pf, vhf, zacc[nt],
                                                           0, 0, 0);
        zacc[nt] = __builtin_amdgcn_mfma_f32_16x16x32_bf16(pf, vlf, zacc[nt],
                                                           0, 0, 0);
      }
    }
  }

#pragma unroll
  for (int r = 0; r < 4; ++r) {
    float v = lsum[r];
#pragma unroll
    for (int off = 1; off < 16; off <<= 1) v += __shfl_xor(v, off);
    lsum[r] = 1.0f / v;
  }
#pragma unroll
  for (int r = 0; r < 4; ++r) {
    const int qrow = wq0 + qd * 4 + r;
#pragma unroll
    for (int nt = 0; nt < 4; ++nt) {
      const float val = zacc[nt][r] * lsum[r];
      const size_t idx =
          ((size_t)bb * TSEQ + qrow) * DOUT + hh * HDIM + nt * 16 + lr;
      u16 hh16, ll16;
      f32_to_bf16pair(val, hh16, ll16);
      zh[idx] = hh16;
      zl[idx] = ll16;
    }
  }
}

// ===========================================================================
extern "C" void kernel_launch(void* const* d_in, const int* in_sizes, int n_in,
                              void* d_out, int out_size, void* d_ws,
                              size_t ws_size, hipStream_t stream) {
  const float* Q = (const float*)d_in[0];
  const float* K = (const float*)d_in[1];
  const float* V = (const float*)d_in[2];
  const int* mask = (const int*)d_in[3];
  const float* Wq = (const float*)d_in[4];
  const float* Wk = (const float*)d_in[5];
  const float* Wv = (const float*)d_in[6];
  const float* Wo = (const float*)d_in[7];
  float* out = (float*)d_out;
  dim3 blk(256);

  // ws map (MiB units; ws >= 128 MiB confirmed on this harness in R5/R6):
  u16* base = (u16*)d_ws;
  auto U = [&](size_t mib) { return base + mib * 524288; };
  float* C0 = (float*)U(0);  // 16 MiB partial out
  float* C1 = (float*)U(16); // 16 MiB partial out
  u64* bits = (u64*)U(32);   // 1 MiB bit mask
  u16 *Wqh = U(48), *Wql = U(50), *Wkh = U(52), *Wkl = U(54), *Wvh = U(56),
      *Wvl = U(58), *Woh = U(60), *Wol = U(62);
  u16 *qh = U(64), *ql = U(72), *kh = U(80), *kl = U(88), *vth = U(96),
      *vtl = U(104);
  u16 *zh = U(112), *zl = U(120);

  mask_pack<<<dim3(1024), blk, 0, stream>>>(mask, bits);
  splitWt<<<dim3(16, 16, 4), blk, 0, stream>>>(Wq, Wk, Wv, Wo, Wqh, Wql, Wkh,
                                               Wkl, Wvh, Wvl, Woh, Wol);
  QkvArgs ga;
  ga.p[0] = {Q, Wqh, Wql, qh, ql, 0};
  ga.p[1] = {K, Wkh, Wkl, kh, kl, 0};
  ga.p[2] = {V, Wvh, Wvl, vth, vtl, 2};
  gemm_qkv<<<dim3(8, 32, 3), blk, 0, stream>>>(ga);
  attn64q<<<dim3(1024), blk, 0, stream>>>(qh, ql, kh, kl, vth, vtl, bits, zh,
                                          zl);
  gemm_out<<<dim3(8, 32, 2), blk, 0, stream>>>(zh, zl, Woh, Wol, C0, C1);
  sumC<<<dim3(4096), blk, 0, stream>>>(C0, C1, out);
}

// Round 8
// 429.957 us; speedup vs baseline: 1.0546x; 1.0546x over previous
//
#include <hip/hip_runtime.h>
#include <math.h>

#define DIN 1024
#define DOUT 1024
#define NHEAD 16
#define HDIM 64
#define BATCH 2
#define TSEQ 2048
#define MROWS (BATCH * TSEQ) // 4096

typedef unsigned short u16;
typedef unsigned long long u64;
typedef __attribute__((ext_vector_type(8))) short short8;
typedef __attribute__((ext_vector_type(4))) float f32x4;
typedef __attribute__((ext_vector_type(4))) unsigned short us4;

// round-to-nearest-even split of fp32 into bf16 hi + bf16 lo (x ~= hi + lo)
__device__ __forceinline__ void f32_to_bf16pair(float x, u16& hi, u16& lo) {
  unsigned u = __float_as_uint(x);
  unsigned r = (u + 0x7fffu + ((u >> 16) & 1u)) & 0xffff0000u;
  hi = (u16)(r >> 16);
  float rem = x - __uint_as_float(r);
  unsigned u2 = __float_as_uint(rem);
  lo = (u16)((u2 + 0x7fffu + ((u2 >> 16) & 1u)) >> 16);
}

// async 16B global->LDS (dst = wave-uniform base, HW adds lane*16)
__device__ __forceinline__ void gld_lds16(const void* g, void* l) {
  __builtin_amdgcn_global_load_lds(
      (__attribute__((address_space(1))) void*)g,
      (__attribute__((address_space(3))) void*)l, 16, 0, 0);
}

// ===========================================================================
// prep: fused preprocessing, one launch.
//   blocks [0,12288):  splitA  — Q/K/V fp32 -> bf16 hi/lo [M][K]
//   blocks [12288,13312): splitWt — W fp32 [K][N] -> bf16 hi/lo W^T [N][K]
//   blocks [13312,14336): mask_pack — int mask -> u64 bit rows at U(112)
// ===========================================================================
__global__ __launch_bounds__(256) void prep(
    const float* __restrict__ Q, const float* __restrict__ K,
    const float* __restrict__ V, const int* __restrict__ mask,
    const float* __restrict__ Wq, const float* __restrict__ Wk,
    const float* __restrict__ Wv, const float* __restrict__ Wo,
    u16* __restrict__ base) {
  const int b = blockIdx.x;
  const int tid = threadIdx.x;
  if (b < 12288) { // ---- splitA ----
    const int z = b >> 12;
    const int i = b & 4095;
    const float* S = z == 0 ? Q : z == 1 ? K : V;
    u16* H = base + (size_t)(16 * z) * 524288;
    u16* L = base + (size_t)(16 * z + 8) * 524288;
    const size_t idx = ((size_t)i * 256 + tid) * 4;
    float4 v = *(const float4*)&S[idx];
    us4 h4, l4;
    u16 hh, ll;
    f32_to_bf16pair(v.x, hh, ll);
    h4[0] = hh; l4[0] = ll;
    f32_to_bf16pair(v.y, hh, ll);
    h4[1] = hh; l4[1] = ll;
    f32_to_bf16pair(v.z, hh, ll);
    h4[2] = hh; l4[2] = ll;
    f32_to_bf16pair(v.w, hh, ll);
    h4[3] = hh; l4[3] = ll;
    *(us4*)&H[idx] = h4;
    *(us4*)&L[idx] = l4;
  } else if (b < 13312) { // ---- splitWt ----
    __shared__ float ts[64][68];
    const int bb = b - 12288;
    const int z = bb >> 8;
    const int rem = bb & 255;
    const int n0 = (rem & 15) * 64, k0 = (rem >> 4) * 64;
    const float* W = z == 0 ? Wq : z == 1 ? Wk : z == 2 ? Wv : Wo;
    u16* H = base + (size_t)(48 + 4 * z) * 524288;
    u16* L = base + (size_t)(50 + 4 * z) * 524288;
    {
      const int kl = tid >> 2, nc = (tid & 3) * 16;
#pragma unroll
      for (int c = 0; c < 4; ++c)
        *(float4*)&ts[kl][nc + c * 4] =
            *(const float4*)&W[(size_t)(k0 + kl) * DOUT + n0 + nc + c * 4];
    }
    __syncthreads();
    const int nl = tid >> 2, kc = (tid & 3) * 16;
#pragma unroll
    for (int g = 0; g < 4; ++g) {
      us4 h4, l4;
#pragma unroll
      for (int j = 0; j < 4; ++j) {
        u16 hh, ll;
        f32_to_bf16pair(ts[kc + g * 4 + j][nl], hh, ll);
        h4[j] = hh;
        l4[j] = ll;
      }
      const size_t idx = (size_t)(n0 + nl) * DIN + k0 + kc + g * 4;
      *(us4*)&H[idx] = h4;
      *(us4*)&L[idx] = l4;
    }
  } else { // ---- mask_pack ----
    const int bb = b - 13312;
    const int gw = bb * 4 + (tid >> 6); // 0..4095 = b*T + t
    const int lane = tid & 63;
    const int* row = mask + (size_t)gw * TSEQ;
    u64* bits = (u64*)(base + (size_t)112 * 524288);
    u64* orow = bits + (size_t)gw * (TSEQ / 64);
#pragma unroll 4
    for (int kt = 0; kt < TSEQ / 64; ++kt) {
      int m = row[kt * 64 + lane];
      u64 bl = __ballot(m != 0);
      if (lane == 0) orow[kt] = bl;
    }
  }
}

// ===========================================================================
// Split-bf16 MFMA GEMM for Q/K/V projections (3-pass Markidis), round-6 form
// (pre-split A: the fused in-register split regressed via LDS conflicts, R7).
// Tile 128x128, BK=32, 4 waves. LDS rows = [32 hi | 32 lo] XOR-swizzled.
// mode 0: out bf16 hi/lo (b,h,t,d);  mode 2: bf16 hi/lo (b,h,d,t).
// ===========================================================================
struct GemmPtrs {
  const u16* Ah;
  const u16* Al;
  const u16* Bh;
  const u16* Bl;
  u16* Oh;
  u16* Ol;
  int mode;
};
struct GemmArgs {
  GemmPtrs p[3];
};

__global__ __launch_bounds__(256) void gemm_qkv(GemmArgs args) {
  const GemmPtrs P = args.p[blockIdx.z];
  __shared__ alignas(16) u16 Abuf[128 * 64];
  __shared__ alignas(16) u16 Bbuf[128 * 64];
  const int tid = threadIdx.x;
  const int w = tid >> 6, lane = tid & 63;
  const int lr = lane & 15, qd = lane >> 4;
  const int mw = w >> 1, nw = w & 1;
  const int n0 = blockIdx.x * 128, m0 = blockIdx.y * 128;

  const u16* gA[4];
  const u16* gB[4];
  u16* lA[4];
  u16* lB[4];
  {
    const int cl = lane & 7;
#pragma unroll
    for (int is = 0; is < 4; ++is) {
      const int row = is * 32 + w * 8 + (lane >> 3);
      const int cg = cl ^ (row & 7);
      gA[is] = (cg < 4 ? P.Ah : P.Al) + (size_t)(m0 + row) * DIN + (cg & 3) * 8;
      gB[is] = (cg < 4 ? P.Bh : P.Bl) + (size_t)(n0 + row) * DIN + (cg & 3) * 8;
      lA[is] = Abuf + (size_t)(is * 32 + w * 8) * 64;
      lB[is] = Bbuf + (size_t)(is * 32 + w * 8) * 64;
    }
  }

  f32x4 acc[4][4] = {};

  for (int kt = 0; kt < 32; ++kt) {
    __syncthreads();
#pragma unroll
    for (int is = 0; is < 4; ++is) {
      gld_lds16(gA[is], lA[is]);
      gld_lds16(gB[is], lB[is]);
      gA[is] += 32;
      gB[is] += 32;
    }
    __syncthreads();

    short8 af[4][2], bf[4][2];
#pragma unroll
    for (int t = 0; t < 4; ++t) {
      const int ra = mw * 64 + t * 16 + lr;
      af[t][0] = *(const short8*)&Abuf[ra * 64 + ((qd ^ (ra & 7)) << 3)];
      af[t][1] = *(const short8*)&Abuf[ra * 64 + (((qd + 4) ^ (ra & 7)) << 3)];
      const int rb = nw * 64 + t * 16 + lr;
      bf[t][0] = *(const short8*)&Bbuf[rb * 64 + ((qd ^ (rb & 7)) << 3)];
      bf[t][1] = *(const short8*)&Bbuf[rb * 64 + (((qd + 4) ^ (rb & 7)) << 3)];
    }
#pragma unroll
    for (int mt = 0; mt < 4; ++mt)
#pragma unroll
      for (int nt = 0; nt < 4; ++nt) {
        acc[mt][nt] = __builtin_amdgcn_mfma_f32_16x16x32_bf16(
            af[mt][0], bf[nt][0], acc[mt][nt], 0, 0, 0);
        acc[mt][nt] = __builtin_amdgcn_mfma_f32_16x16x32_bf16(
            af[mt][0], bf[nt][1], acc[mt][nt], 0, 0, 0);
        acc[mt][nt] = __builtin_amdgcn_mfma_f32_16x16x32_bf16(
            af[mt][1], bf[nt][0], acc[mt][nt], 0, 0, 0);
      }
  }

#pragma unroll
  for (int mt = 0; mt < 4; ++mt)
#pragma unroll
    for (int nt = 0; nt < 4; ++nt)
#pragma unroll
      for (int r = 0; r < 4; ++r) {
        const float val = acc[mt][nt][r];
        const int gm = m0 + mw * 64 + mt * 16 + qd * 4 + r;
        const int gn = n0 + nw * 64 + nt * 16 + lr;
        u16 hh16, ll16;
        f32_to_bf16pair(val, hh16, ll16);
        const int bb = gm >> 11, t = gm & 2047;
        const int h = gn >> 6, d = gn & 63;
        size_t idx;
        if (P.mode == 0)
          idx = (((size_t)(bb * NHEAD + h) * TSEQ) + t) * HDIM + d;
        else
          idx = (((size_t)(bb * NHEAD + h) * HDIM) + d) * TSEQ + t;
        P.Oh[idx] = hh16;
        P.Ol[idx] = ll16;
      }
}

// ===========================================================================
// Out-projection GEMM (single dispatch, K=1024), writes fp32 out directly.
// ===========================================================================
__global__ __launch_bounds__(256) void gemm_out(
    const u16* __restrict__ Ah, const u16* __restrict__ Al,
    const u16* __restrict__ Bh, const u16* __restrict__ Bl,
    float* __restrict__ Of) {
  __shared__ alignas(16) u16 Abuf[128 * 64];
  __shared__ alignas(16) u16 Bbuf[128 * 64];
  const int tid = threadIdx.x;
  const int w = tid >> 6, lane = tid & 63;
  const int lr = lane & 15, qd = lane >> 4;
  const int mw = w >> 1, nw = w & 1;
  const int n0 = blockIdx.x * 128, m0 = blockIdx.y * 128;

  const u16* gA[4];
  const u16* gB[4];
  u16* lA[4];
  u16* lB[4];
  {
    const int cl = lane & 7;
#pragma unroll
    for (int is = 0; is < 4; ++is) {
      const int row = is * 32 + w * 8 + (lane >> 3);
      const int cg = cl ^ (row & 7);
      gA[is] = (cg < 4 ? Ah : Al) + (size_t)(m0 + row) * DIN + (cg & 3) * 8;
      gB[is] = (cg < 4 ? Bh : Bl) + (size_t)(n0 + row) * DIN + (cg & 3) * 8;
      lA[is] = Abuf + (size_t)(is * 32 + w * 8) * 64;
      lB[is] = Bbuf + (size_t)(is * 32 + w * 8) * 64;
    }
  }

  f32x4 acc[4][4] = {};

  for (int kt = 0; kt < 32; ++kt) {
    __syncthreads();
#pragma unroll
    for (int is = 0; is < 4; ++is) {
      gld_lds16(gA[is], lA[is]);
      gld_lds16(gB[is], lB[is]);
      gA[is] += 32;
      gB[is] += 32;
    }
    __syncthreads();

    short8 af[4][2], bf[4][2];
#pragma unroll
    for (int t = 0; t < 4; ++t) {
      const int ra = mw * 64 + t * 16 + lr;
      af[t][0] = *(const short8*)&Abuf[ra * 64 + ((qd ^ (ra & 7)) << 3)];
      af[t][1] = *(const short8*)&Abuf[ra * 64 + (((qd + 4) ^ (ra & 7)) << 3)];
      const int rb = nw * 64 + t * 16 + lr;
      bf[t][0] = *(const short8*)&Bbuf[rb * 64 + ((qd ^ (rb & 7)) << 3)];
      bf[t][1] = *(const short8*)&Bbuf[rb * 64 + (((qd + 4) ^ (rb & 7)) << 3)];
    }
#pragma unroll
    for (int mt = 0; mt < 4; ++mt)
#pragma unroll
      for (int nt = 0; nt < 4; ++nt) {
        acc[mt][nt] = __builtin_amdgcn_mfma_f32_16x16x32_bf16(
            af[mt][0], bf[nt][0], acc[mt][nt], 0, 0, 0);
        acc[mt][nt] = __builtin_amdgcn_mfma_f32_16x16x32_bf16(
            af[mt][0], bf[nt][1], acc[mt][nt], 0, 0, 0);
        acc[mt][nt] = __builtin_amdgcn_mfma_f32_16x16x32_bf16(
            af[mt][1], bf[nt][0], acc[mt][nt], 0, 0, 0);
      }
  }

#pragma unroll
  for (int mt = 0; mt < 4; ++mt)
#pragma unroll
    for (int nt = 0; nt < 4; ++nt)
#pragma unroll
      for (int r = 0; r < 4; ++r) {
        const int gm = m0 + mw * 64 + mt * 16 + qd * 4 + r;
        const int gn = n0 + nw * 64 + nt * 16 + lr;
        Of[(size_t)gm * DOUT + gn] = acc[mt][nt][r];
      }
}

// ===========================================================================
// MFMA flash attention, 64 q-rows per block (4 waves x 16 rows), 1024 blocks.
// XCD-aware remap; K/V staged via async global_load_lds (global-side XOR
// swizzle); mask from the 1 MiB bit-pack. LDS 40 KB -> 4 blocks/CU.
// z written as bf16 hi/lo row-major (aliases the dead Qh/Ql ws region).
// ===========================================================================
__global__ __launch_bounds__(256, 4) void attn64q(
    const u16* __restrict__ qh, const u16* __restrict__ ql,
    const u16* __restrict__ kh, const u16* __restrict__ kl,
    const u16* __restrict__ vh, const u16* __restrict__ vl,
    const u64* __restrict__ bits, u16* __restrict__ zh,
    u16* __restrict__ zl) {
  __shared__ alignas(16) u16 lds_k[2][64 * 64]; // [hi/lo][key][d]
  __shared__ alignas(16) u16 lds_v[2][64 * 64]; // [hi/lo][d][key]
  __shared__ alignas(16) u16 lds_p[4][16 * 64]; // [wave][q][key]
  const int tid = threadIdx.x;
  const int w = tid >> 6, lane = tid & 63;
  const int lr = lane & 15, qd = lane >> 4;
  const int L = blockIdx.x;
  const int bh = (L & 7) + 8 * ((L >> 3) & 3);
  const int qt0 = (L >> 5) * 64;
  const int bb = bh >> 4, hh = bh & 15;
  const int wq0 = qt0 + w * 16;
  const size_t bh_off = (size_t)bh * TSEQ * HDIM;

  short8 qf[2][2];
#pragma unroll
  for (int ks = 0; ks < 2; ++ks) {
    const size_t off = bh_off + (size_t)(wq0 + lr) * HDIM + ks * 32 + qd * 8;
    qf[ks][0] = *(const short8*)(qh + off);
    qf[ks][1] = *(const short8*)(ql + off);
  }

  f32x4 zacc[4] = {};
  float lsum[4] = {};

  const u16* ssrc = (w == 0 ? kh : w == 1 ? kl : w == 2 ? vh : vl) + bh_off;
  u16* sdst = (w < 2) ? &lds_k[w][0] : &lds_v[w - 2][0];
  const bool isk = (w < 2);
  const int srow = lane >> 3, scl = lane & 7;
  const u64* brow = bits + ((size_t)bb * TSEQ + wq0 + qd * 4) * (TSEQ / 64);

  for (int kt0 = 0; kt0 < TSEQ; kt0 += 64) {
    __syncthreads();
#pragma unroll
    for (int is = 0; is < 8; ++is) {
      const int row = is * 8 + srow;
      const int cg = scl ^ (row & 7);
      const u16* src = isk ? ssrc + (size_t)(kt0 + row) * HDIM + cg * 8
                           : ssrc + (size_t)row * TSEQ + kt0 + cg * 8;
      gld_lds16(src, sdst + is * 512);
    }
    __syncthreads();

    u64 bm[4];
#pragma unroll
    for (int r = 0; r < 4; ++r) bm[r] = brow[r * (TSEQ / 64) + (kt0 >> 6)];

    // S = Q K^T, 3-pass split
    f32x4 sacc[4] = {};
#pragma unroll
    for (int ks = 0; ks < 2; ++ks)
#pragma unroll
      for (int nt = 0; nt < 4; ++nt) {
        const int krow = nt * 16 + lr;
        const int chunk = (((ks * 4 + qd) ^ (krow & 7)) << 3);
        short8 bhf = *(const short8*)&lds_k[0][krow * 64 + chunk];
        short8 blf = *(const short8*)&lds_k[1][krow * 64 + chunk];
        sacc[nt] = __builtin_amdgcn_mfma_f32_16x16x32_bf16(qf[ks][0], bhf,
                                                           sacc[nt], 0, 0, 0);
        sacc[nt] = __builtin_amdgcn_mfma_f32_16x16x32_bf16(qf[ks][0], blf,
                                                           sacc[nt], 0, 0, 0);
        sacc[nt] = __builtin_amdgcn_mfma_f32_16x16x32_bf16(qf[ks][1], bhf,
                                                           sacc[nt], 0, 0, 0);
      }

    // p = exp(scale*s) or 0; quantize to bf16; accumulate l over quantized p
    u16* pw = &lds_p[w][0];
#pragma unroll
    for (int nt = 0; nt < 4; ++nt)
#pragma unroll
      for (int r = 0; r < 4; ++r) {
        float s = sacc[nt][r];
        const unsigned keep = (unsigned)(bm[r] >> (nt * 16 + lr)) & 1u;
        s = keep ? s * 0.125f : -1.0e9f;
        float p = __expf(s);
        unsigned u = (__float_as_uint(p) + 0x8000u) & 0xffff0000u;
        lsum[r] += __uint_as_float(u);
        const int prow = qd * 4 + r;
        const int pcol = nt * 16 + lr;
        pw[prow * 64 + ((((pcol >> 3) ^ (prow & 7)) << 3)) + (pcol & 7)] =
            (u16)(u >> 16);
      }

    // Z += P V (V hi/lo 2-pass)
#pragma unroll
    for (int ks = 0; ks < 2; ++ks) {
      const int chunkp = (((ks * 4 + qd) ^ (lr & 7)) << 3);
      short8 pf = *(const short8*)&pw[lr * 64 + chunkp];
#pragma unroll
      for (int nt = 0; nt < 4; ++nt) {
        const int vrow = nt * 16 + lr;
        const int chunk = (((ks * 4 + qd) ^ (vrow & 7)) << 3);
        short8 vhf = *(const short8*)&lds_v[0][vrow * 64 + chunk];
        short8 vlf = *(const short8*)&lds_v[1][vrow * 64 + chunk];
        zacc[nt] = __builtin_amdgcn_mfma_f32_16x16x32_bf16(pf, vhf, zacc[nt],
                                                           0, 0, 0);
        zacc[nt] = __builtin_amdgcn_mfma_f32_16x16x32_bf16(pf, vlf, zacc[nt],
                                                           0, 0, 0);
      }
    }
  }

#pragma unroll
  for (int r = 0; r < 4; ++r) {
    float v = lsum[r];
#pragma unroll
    for (int off = 1; off < 16; off <<= 1) v += __shfl_xor(v, off);
    lsum[r] = 1.0f / v;
  }
#pragma unroll
  for (int r = 0; r < 4; ++r) {
    const int qrow = wq0 + qd * 4 + r;
#pragma unroll
    for (int nt = 0; nt < 4; ++nt) {
      const float val = zacc[nt][r] * lsum[r];
      const size_t idx =
          ((size_t)bb * TSEQ + qrow) * DOUT + hh * HDIM + nt * 16 + lr;
      u16 hh16, ll16;
      f32_to_bf16pair(val, hh16, ll16);
      zh[idx] = hh16;
      zl[idx] = ll16;
    }
  }
}

// ===========================================================================
extern "C" void kernel_launch(void* const* d_in, const int* in_sizes, int n_in,
                              void* d_out, int out_size, void* d_ws,
                              size_t ws_size, hipStream_t stream) {
  const float* Q = (const float*)d_in[0];
  const float* K = (const float*)d_in[1];
  const float* V = (const float*)d_in[2];
  const int* mask = (const int*)d_in[3];
  const float* Wq = (const float*)d_in[4];
  const float* Wk = (const float*)d_in[5];
  const float* Wv = (const float*)d_in[6];
  const float* Wo = (const float*)d_in[7];
  float* out = (float*)d_out;
  dim3 blk(256);

  // ws map (1 MiB units, 128 MiB total — proven available):
  //  0..48  Q/K/V hi+lo splits (8 MiB each)   [dead after gemm_qkv]
  //  0..16  zh/zl (aliases Qh/Ql, written by attn)
  // 48..64  W^T hi/lo x4 (2 MiB each)
  // 64..112 q/k/v projections hi/lo (8 MiB each)
  // 112..113 mask bit-pack (1 MiB)
  u16* base = (u16*)d_ws;
  auto U = [&](size_t mib) { return base + mib * 524288; };
  u16 *Qh = U(0), *Ql = U(8), *Kh = U(16), *Kl = U(24), *Vh = U(32),
      *Vl = U(40);
  u16 *Wqh = U(48), *Wql = U(50), *Wkh = U(52), *Wkl = U(54), *Wvh = U(56),
      *Wvl = U(58), *Woh = U(60), *Wol = U(62);
  u16 *qh = U(64), *ql = U(72), *kh = U(80), *kl = U(88), *vth = U(96),
      *vtl = U(104);
  u16 *zh = U(0), *zl = U(8); // alias Qh/Ql
  u64* bits = (u64*)U(112);

  prep<<<dim3(14336), blk, 0, stream>>>(Q, K, V, mask, Wq, Wk, Wv, Wo, base);
  GemmArgs ga;
  ga.p[0] = {Qh, Ql, Wqh, Wql, qh, ql, 0};
  ga.p[1] = {Kh, Kl, Wkh, Wkl, kh, kl, 0};
  ga.p[2] = {Vh, Vl, Wvh, Wvl, vth, vtl, 2};
  gemm_qkv<<<dim3(8, 32, 3), blk, 0, stream>>>(ga);
  attn64q<<<dim3(1024), blk, 0, stream>>>(qh, ql, kh, kl, vth, vtl, bits, zh,
                                          zl);
  gemm_out<<<dim3(8, 32), blk, 0, stream>>>(zh, zl, Woh, Wol, out);
}

// Round 9
// 408.774 us; speedup vs baseline: 1.1092x; 1.0518x over previous
//
#include <hip/hip_runtime.h>
#include <math.h>

#define DIN 1024
#define DOUT 1024
#define NHEAD 16
#define HDIM 64
#define BATCH 2
#define TSEQ 2048
#define MROWS (BATCH * TSEQ) // 4096

typedef unsigned short u16;
typedef unsigned long long u64;
typedef __attribute__((ext_vector_type(8))) short short8;
typedef __attribute__((ext_vector_type(4))) float f32x4;
typedef __attribute__((ext_vector_type(4))) unsigned short us4;

// round-to-nearest-even split of fp32 into bf16 hi + bf16 lo (x ~= hi + lo)
__device__ __forceinline__ void f32_to_bf16pair(float x, u16& hi, u16& lo) {
  unsigned u = __float_as_uint(x);
  unsigned r = (u + 0x7fffu + ((u >> 16) & 1u)) & 0xffff0000u;
  hi = (u16)(r >> 16);
  float rem = x - __uint_as_float(r);
  unsigned u2 = __float_as_uint(rem);
  lo = (u16)((u2 + 0x7fffu + ((u2 >> 16) & 1u)) >> 16);
}

// async 16B global->LDS (dst = wave-uniform base, HW adds lane*16)
__device__ __forceinline__ void gld_lds16(const void* g, void* l) {
  __builtin_amdgcn_global_load_lds(
      (__attribute__((address_space(1))) void*)g,
      (__attribute__((address_space(3))) void*)l, 16, 0, 0);
}

// ===========================================================================
// prep: fused preprocessing, one launch (R8 form, kept).
// ===========================================================================
__global__ __launch_bounds__(256) void prep(
    const float* __restrict__ Q, const float* __restrict__ K,
    const float* __restrict__ V, const int* __restrict__ mask,
    const float* __restrict__ Wq, const float* __restrict__ Wk,
    const float* __restrict__ Wv, const float* __restrict__ Wo,
    u16* __restrict__ base) {
  const int b = blockIdx.x;
  const int tid = threadIdx.x;
  if (b < 12288) { // ---- splitA ----
    const int z = b >> 12;
    const int i = b & 4095;
    const float* S = z == 0 ? Q : z == 1 ? K : V;
    u16* H = base + (size_t)(16 * z) * 524288;
    u16* L = base + (size_t)(16 * z + 8) * 524288;
    const size_t idx = ((size_t)i * 256 + tid) * 4;
    float4 v = *(const float4*)&S[idx];
    us4 h4, l4;
    u16 hh, ll;
    f32_to_bf16pair(v.x, hh, ll);
    h4[0] = hh; l4[0] = ll;
    f32_to_bf16pair(v.y, hh, ll);
    h4[1] = hh; l4[1] = ll;
    f32_to_bf16pair(v.z, hh, ll);
    h4[2] = hh; l4[2] = ll;
    f32_to_bf16pair(v.w, hh, ll);
    h4[3] = hh; l4[3] = ll;
    *(us4*)&H[idx] = h4;
    *(us4*)&L[idx] = l4;
  } else if (b < 13312) { // ---- splitWt ----
    __shared__ float ts[64][68];
    const int bb = b - 12288;
    const int z = bb >> 8;
    const int rem = bb & 255;
    const int n0 = (rem & 15) * 64, k0 = (rem >> 4) * 64;
    const float* W = z == 0 ? Wq : z == 1 ? Wk : z == 2 ? Wv : Wo;
    u16* H = base + (size_t)(48 + 4 * z) * 524288;
    u16* L = base + (size_t)(50 + 4 * z) * 524288;
    {
      const int kl = tid >> 2, nc = (tid & 3) * 16;
#pragma unroll
      for (int c = 0; c < 4; ++c)
        *(float4*)&ts[kl][nc + c * 4] =
            *(const float4*)&W[(size_t)(k0 + kl) * DOUT + n0 + nc + c * 4];
    }
    __syncthreads();
    const int nl = tid >> 2, kc = (tid & 3) * 16;
#pragma unroll
    for (int g = 0; g < 4; ++g) {
      us4 h4, l4;
#pragma unroll
      for (int j = 0; j < 4; ++j) {
        u16 hh, ll;
        f32_to_bf16pair(ts[kc + g * 4 + j][nl], hh, ll);
        h4[j] = hh;
        l4[j] = ll;
      }
      const size_t idx = (size_t)(n0 + nl) * DIN + k0 + kc + g * 4;
      *(us4*)&H[idx] = h4;
      *(us4*)&L[idx] = l4;
    }
  } else { // ---- mask_pack ----
    const int bb = b - 13312;
    const int gw = bb * 4 + (tid >> 6);
    const int lane = tid & 63;
    const int* row = mask + (size_t)gw * TSEQ;
    u64* bits = (u64*)(base + (size_t)112 * 524288);
    u64* orow = bits + (size_t)gw * (TSEQ / 64);
#pragma unroll 4
    for (int kt = 0; kt < TSEQ / 64; ++kt) {
      int m = row[kt * 64 + lane];
      u64 bl = __ballot(m != 0);
      if (lane == 0) orow[kt] = bl;
    }
  }
}

// ===========================================================================
// Split-bf16 MFMA GEMM for Q/K/V projections (3-pass Markidis).
// Tile 128x128, BK=32, 4 waves, XOR-swizzled LDS. XCD m-strip swizzle:
// XCD i (= blockIdx.x under flat%8 dispatch) owns m-tiles 4i..4i+3 across
// all n, shrinking per-XCD L2 working set (full-A -> 2 MB strip + 4 MB B).
// mode 0: out bf16 hi/lo (b,h,t,d);  mode 2: bf16 hi/lo (b,h,d,t).
// ===========================================================================
struct GemmPtrs {
  const u16* Ah;
  const u16* Al;
  const u16* Bh;
  const u16* Bl;
  u16* Oh;
  u16* Ol;
  int mode;
};
struct GemmArgs {
  GemmPtrs p[3];
};

__global__ __launch_bounds__(256) void gemm_qkv(GemmArgs args) {
  const GemmPtrs P = args.p[blockIdx.z];
  __shared__ alignas(16) u16 Abuf[128 * 64];
  __shared__ alignas(16) u16 Bbuf[128 * 64];
  const int tid = threadIdx.x;
  const int w = tid >> 6, lane = tid & 63;
  const int lr = lane & 15, qd = lane >> 4;
  const int mw = w >> 1, nw = w & 1;
  // XCD m-strip swizzle: m-tile = 4*x + (y&3), n-tile = y>>2
  const int m0 = (blockIdx.x * 4 + (blockIdx.y & 3)) * 128;
  const int n0 = (blockIdx.y >> 2) * 128;

  const u16* gA[4];
  const u16* gB[4];
  u16* lA[4];
  u16* lB[4];
  {
    const int cl = lane & 7;
#pragma unroll
    for (int is = 0; is < 4; ++is) {
      const int row = is * 32 + w * 8 + (lane >> 3);
      const int cg = cl ^ (row & 7);
      gA[is] = (cg < 4 ? P.Ah : P.Al) + (size_t)(m0 + row) * DIN + (cg & 3) * 8;
      gB[is] = (cg < 4 ? P.Bh : P.Bl) + (size_t)(n0 + row) * DIN + (cg & 3) * 8;
      lA[is] = Abuf + (size_t)(is * 32 + w * 8) * 64;
      lB[is] = Bbuf + (size_t)(is * 32 + w * 8) * 64;
    }
  }

  f32x4 acc[4][4] = {};

  for (int kt = 0; kt < 32; ++kt) {
    __syncthreads();
#pragma unroll
    for (int is = 0; is < 4; ++is) {
      gld_lds16(gA[is], lA[is]);
      gld_lds16(gB[is], lB[is]);
      gA[is] += 32;
      gB[is] += 32;
    }
    __syncthreads();

    short8 af[4][2], bf[4][2];
#pragma unroll
    for (int t = 0; t < 4; ++t) {
      const int ra = mw * 64 + t * 16 + lr;
      af[t][0] = *(const short8*)&Abuf[ra * 64 + ((qd ^ (ra & 7)) << 3)];
      af[t][1] = *(const short8*)&Abuf[ra * 64 + (((qd + 4) ^ (ra & 7)) << 3)];
      const int rb = nw * 64 + t * 16 + lr;
      bf[t][0] = *(const short8*)&Bbuf[rb * 64 + ((qd ^ (rb & 7)) << 3)];
      bf[t][1] = *(const short8*)&Bbuf[rb * 64 + (((qd + 4) ^ (rb & 7)) << 3)];
    }
#pragma unroll
    for (int mt = 0; mt < 4; ++mt)
#pragma unroll
      for (int nt = 0; nt < 4; ++nt) {
        acc[mt][nt] = __builtin_amdgcn_mfma_f32_16x16x32_bf16(
            af[mt][0], bf[nt][0], acc[mt][nt], 0, 0, 0);
        acc[mt][nt] = __builtin_amdgcn_mfma_f32_16x16x32_bf16(
            af[mt][0], bf[nt][1], acc[mt][nt], 0, 0, 0);
        acc[mt][nt] = __builtin_amdgcn_mfma_f32_16x16x32_bf16(
            af[mt][1], bf[nt][0], acc[mt][nt], 0, 0, 0);
      }
  }

#pragma unroll
  for (int mt = 0; mt < 4; ++mt)
#pragma unroll
    for (int nt = 0; nt < 4; ++nt)
#pragma unroll
      for (int r = 0; r < 4; ++r) {
        const float val = acc[mt][nt][r];
        const int gm = m0 + mw * 64 + mt * 16 + qd * 4 + r;
        const int gn = n0 + nw * 64 + nt * 16 + lr;
        u16 hh16, ll16;
        f32_to_bf16pair(val, hh16, ll16);
        const int bb = gm >> 11, t = gm & 2047;
        const int h = gn >> 6, d = gn & 63;
        size_t idx;
        if (P.mode == 0)
          idx = (((size_t)(bb * NHEAD + h) * TSEQ) + t) * HDIM + d;
        else
          idx = (((size_t)(bb * NHEAD + h) * HDIM) + d) * TSEQ + t;
        P.Oh[idx] = hh16;
        P.Ol[idx] = ll16;
      }
}

// ===========================================================================
// Out-projection GEMM, K-split x2 (blockIdx.z = K-half) -> partial fp32
// buffers C0/C1 (deterministic; summed by sumC). 512 blocks = 2/CU.
// (Single-dispatch 256-block version measured ~25 us slower in R8 — 1
//  block/CU is latency-starved. Keep the split.)
// ===========================================================================
__global__ __launch_bounds__(256) void gemm_out(
    const u16* __restrict__ Ah, const u16* __restrict__ Al,
    const u16* __restrict__ Bh, const u16* __restrict__ Bl,
    float* __restrict__ C0, float* __restrict__ C1) {
  float* Of = blockIdx.z == 0 ? C0 : C1;
  const int koff = blockIdx.z * 512;
  __shared__ alignas(16) u16 Abuf[128 * 64];
  __shared__ alignas(16) u16 Bbuf[128 * 64];
  const int tid = threadIdx.x;
  const int w = tid >> 6, lane = tid & 63;
  const int lr = lane & 15, qd = lane >> 4;
  const int mw = w >> 1, nw = w & 1;
  const int n0 = blockIdx.x * 128, m0 = blockIdx.y * 128;

  const u16* gA[4];
  const u16* gB[4];
  u16* lA[4];
  u16* lB[4];
  {
    const int cl = lane & 7;
#pragma unroll
    for (int is = 0; is < 4; ++is) {
      const int row = is * 32 + w * 8 + (lane >> 3);
      const int cg = cl ^ (row & 7);
      gA[is] = (cg < 4 ? Ah : Al) + (size_t)(m0 + row) * DIN + (cg & 3) * 8 + koff;
      gB[is] = (cg < 4 ? Bh : Bl) + (size_t)(n0 + row) * DIN + (cg & 3) * 8 + koff;
      lA[is] = Abuf + (size_t)(is * 32 + w * 8) * 64;
      lB[is] = Bbuf + (size_t)(is * 32 + w * 8) * 64;
    }
  }

  f32x4 acc[4][4] = {};

  for (int kt = 0; kt < 16; ++kt) {
    __syncthreads();
#pragma unroll
    for (int is = 0; is < 4; ++is) {
      gld_lds16(gA[is], lA[is]);
      gld_lds16(gB[is], lB[is]);
      gA[is] += 32;
      gB[is] += 32;
    }
    __syncthreads();

    short8 af[4][2], bf[4][2];
#pragma unroll
    for (int t = 0; t < 4; ++t) {
      const int ra = mw * 64 + t * 16 + lr;
      af[t][0] = *(const short8*)&Abuf[ra * 64 + ((qd ^ (ra & 7)) << 3)];
      af[t][1] = *(const short8*)&Abuf[ra * 64 + (((qd + 4) ^ (ra & 7)) << 3)];
      const int rb = nw * 64 + t * 16 + lr;
      bf[t][0] = *(const short8*)&Bbuf[rb * 64 + ((qd ^ (rb & 7)) << 3)];
      bf[t][1] = *(const short8*)&Bbuf[rb * 64 + (((qd + 4) ^ (rb & 7)) << 3)];
    }
#pragma unroll
    for (int mt = 0; mt < 4; ++mt)
#pragma unroll
      for (int nt = 0; nt < 4; ++nt) {
        acc[mt][nt] = __builtin_amdgcn_mfma_f32_16x16x32_bf16(
            af[mt][0], bf[nt][0], acc[mt][nt], 0, 0, 0);
        acc[mt][nt] = __builtin_amdgcn_mfma_f32_16x16x32_bf16(
            af[mt][0], bf[nt][1], acc[mt][nt], 0, 0, 0);
        acc[mt][nt] = __builtin_amdgcn_mfma_f32_16x16x32_bf16(
            af[mt][1], bf[nt][0], acc[mt][nt], 0, 0, 0);
      }
  }

#pragma unroll
  for (int mt = 0; mt < 4; ++mt)
#pragma unroll
    for (int nt = 0; nt < 4; ++nt)
#pragma unroll
      for (int r = 0; r < 4; ++r) {
        const int gm = m0 + mw * 64 + mt * 16 + qd * 4 + r;
        const int gn = n0 + nw * 64 + nt * 16 + lr;
        Of[(size_t)gm * DOUT + gn] = acc[mt][nt][r];
      }
}

__global__ __launch_bounds__(256) void sumC(const float* __restrict__ A,
                                            const float* __restrict__ B,
                                            float* __restrict__ O) {
  const size_t i = ((size_t)blockIdx.x * 256 + threadIdx.x) * 4;
  float4 a = *(const float4*)&A[i];
  float4 b = *(const float4*)&B[i];
  *(float4*)&O[i] = make_float4(a.x + b.x, a.y + b.y, a.z + b.z, a.w + b.w);
}

// ===========================================================================
// MFMA flash attention (R8 form, kept): 64 q-rows/block, 1024 blocks,
// XCD-aware remap, async K/V staging, bit-packed mask, 4 blocks/CU.
// ===========================================================================
__global__ __launch_bounds__(256, 4) void attn64q(
    const u16* __restrict__ qh, const u16* __restrict__ ql,
    const u16* __restrict__ kh, const u16* __restrict__ kl,
    const u16* __restrict__ vh, const u16* __restrict__ vl,
    const u64* __restrict__ bits, u16* __restrict__ zh,
    u16* __restrict__ zl) {
  __shared__ alignas(16) u16 lds_k[2][64 * 64];
  __shared__ alignas(16) u16 lds_v[2][64 * 64];
  __shared__ alignas(16) u16 lds_p[4][16 * 64];
  const int tid = threadIdx.x;
  const int w = tid >> 6, lane = tid & 63;
  const int lr = lane & 15, qd = lane >> 4;
  const int L = blockIdx.x;
  const int bh = (L & 7) + 8 * ((L >> 3) & 3);
  const int qt0 = (L >> 5) * 64;
  const int bb = bh >> 4, hh = bh & 15;
  const int wq0 = qt0 + w * 16;
  const size_t bh_off = (size_t)bh * TSEQ * HDIM;

  short8 qf[2][2];
#pragma unroll
  for (int ks = 0; ks < 2; ++ks) {
    const size_t off = bh_off + (size_t)(wq0 + lr) * HDIM + ks * 32 + qd * 8;
    qf[ks][0] = *(const short8*)(qh + off);
    qf[ks][1] = *(const short8*)(ql + off);
  }

  f32x4 zacc[4] = {};
  float lsum[4] = {};

  const u16* ssrc = (w == 0 ? kh : w == 1 ? kl : w == 2 ? vh : vl) + bh_off;
  u16* sdst = (w < 2) ? &lds_k[w][0] : &lds_v[w - 2][0];
  const bool isk = (w < 2);
  const int srow = lane >> 3, scl = lane & 7;
  const u64* brow = bits + ((size_t)bb * TSEQ + wq0 + qd * 4) * (TSEQ / 64);

  for (int kt0 = 0; kt0 < TSEQ; kt0 += 64) {
    __syncthreads();
#pragma unroll
    for (int is = 0; is < 8; ++is) {
      const int row = is * 8 + srow;
      const int cg = scl ^ (row & 7);
      const u16* src = isk ? ssrc + (size_t)(kt0 + row) * HDIM + cg * 8
                           : ssrc + (size_t)row * TSEQ + kt0 + cg * 8;
      gld_lds16(src, sdst + is * 512);
    }
    __syncthreads();

    u64 bm[4];
#pragma unroll
    for (int r = 0; r < 4; ++r) bm[r] = brow[r * (TSEQ / 64) + (kt0 >> 6)];

    f32x4 sacc[4] = {};
#pragma unroll
    for (int ks = 0; ks < 2; ++ks)
#pragma unroll
      for (int nt = 0; nt < 4; ++nt) {
        const int krow = nt * 16 + lr;
        const int chunk = (((ks * 4 + qd) ^ (krow & 7)) << 3);
        short8 bhf = *(const short8*)&lds_k[0][krow * 64 + chunk];
        short8 blf = *(const short8*)&lds_k[1][krow * 64 + chunk];
        sacc[nt] = __builtin_amdgcn_mfma_f32_16x16x32_bf16(qf[ks][0], bhf,
                                                           sacc[nt], 0, 0, 0);
        sacc[nt] = __builtin_amdgcn_mfma_f32_16x16x32_bf16(qf[ks][0], blf,
                                                           sacc[nt], 0, 0, 0);
        sacc[nt] = __builtin_amdgcn_mfma_f32_16x16x32_bf16(qf[ks][1], bhf,
                                                           sacc[nt], 0, 0, 0);
      }

    u16* pw = &lds_p[w][0];
#pragma unroll
    for (int nt = 0; nt < 4; ++nt)
#pragma unroll
      for (int r = 0; r < 4; ++r) {
        float s = sacc[nt][r];
        const unsigned keep = (unsigned)(bm[r] >> (nt * 16 + lr)) & 1u;
        s = keep ? s * 0.125f : -1.0e9f;
        float p = __expf(s);
        unsigned u = (__float_as_uint(p) + 0x8000u) & 0xffff0000u;
        lsum[r] += __uint_as_float(u);
        const int prow = qd * 4 + r;
        const int pcol = nt * 16 + lr;
        pw[prow * 64 + ((((pcol >> 3) ^ (prow & 7)) << 3)) + (pcol & 7)] =
            (u16)(u >> 16);
      }

#pragma unroll
    for (int ks = 0; ks < 2; ++ks) {
      const int chunkp = (((ks * 4 + qd) ^ (lr & 7)) << 3);
      short8 pf = *(const short8*)&pw[lr * 64 + chunkp];
#pragma unroll
      for (int nt = 0; nt < 4; ++nt) {
        const int vrow = nt * 16 + lr;
        const int chunk = (((ks * 4 + qd) ^ (vrow & 7)) << 3);
        short8 vhf = *(const short8*)&lds_v[0][vrow * 64 + chunk];
        short8 vlf = *(const short8*)&lds_v[1][vrow * 64 + chunk];
        zacc[nt] = __builtin_amdgcn_mfma_f32_16x16x32_bf16(pf, vhf, zacc[nt],
                                                           0, 0, 0);
        zacc[nt] = __builtin_amdgcn_mfma_f32_16x16x32_bf16(pf, vlf, zacc[nt],
                                                           0, 0, 0);
      }
    }
  }

#pragma unroll
  for (int r = 0; r < 4; ++r) {
    float v = lsum[r];
#pragma unroll
    for (int off = 1; off < 16; off <<= 1) v += __shfl_xor(v, off);
    lsum[r] = 1.0f / v;
  }
#pragma unroll
  for (int r = 0; r < 4; ++r) {
    const int qrow = wq0 + qd * 4 + r;
#pragma unroll
    for (int nt = 0; nt < 4; ++nt) {
      const float val = zacc[nt][r] * lsum[r];
      const size_t idx =
          ((size_t)bb * TSEQ + qrow) * DOUT + hh * HDIM + nt * 16 + lr;
      u16 hh16, ll16;
      f32_to_bf16pair(val, hh16, ll16);
      zh[idx] = hh16;
      zl[idx] = ll16;
    }
  }
}

// ===========================================================================
extern "C" void kernel_launch(void* const* d_in, const int* in_sizes, int n_in,
                              void* d_out, int out_size, void* d_ws,
                              size_t ws_size, hipStream_t stream) {
  const float* Q = (const float*)d_in[0];
  const float* K = (const float*)d_in[1];
  const float* V = (const float*)d_in[2];
  const int* mask = (const int*)d_in[3];
  const float* Wq = (const float*)d_in[4];
  const float* Wk = (const float*)d_in[5];
  const float* Wv = (const float*)d_in[6];
  const float* Wo = (const float*)d_in[7];
  float* out = (float*)d_out;
  dim3 blk(256);

  // ws map (1 MiB units, 128 MiB):
  //  0..48  Q/K/V hi+lo splits (dead after gemm_qkv)
  //  0..16  zh/zl (alias Qh/Ql; written by attn)
  // 16..48  C0/C1 fp32 partials (alias Kh..Vl; written by gemm_out)
  // 48..64  W^T hi/lo x4
  // 64..112 q/k/v projections hi/lo
  // 112..113 mask bit-pack
  u16* base = (u16*)d_ws;
  auto U = [&](size_t mib) { return base + mib * 524288; };
  u16 *Qh = U(0), *Ql = U(8), *Kh = U(16), *Kl = U(24), *Vh = U(32),
      *Vl = U(40);
  u16 *Wqh = U(48), *Wql = U(50), *Wkh = U(52), *Wkl = U(54), *Wvh = U(56),
      *Wvl = U(58), *Woh = U(60), *Wol = U(62);
  u16 *qh = U(64), *ql = U(72), *kh = U(80), *kl = U(88), *vth = U(96),
      *vtl = U(104);
  u16 *zh = U(0), *zl = U(8); // alias Qh/Ql
  float* C0 = (float*)U(16);  // alias Kh/Kl
  float* C1 = (float*)U(32);  // alias Vh/Vl
  u64* bits = (u64*)U(112);

  prep<<<dim3(14336), blk, 0, stream>>>(Q, K, V, mask, Wq, Wk, Wv, Wo, base);
  GemmArgs ga;
  ga.p[0] = {Qh, Ql, Wqh, Wql, qh, ql, 0};
  ga.p[1] = {Kh, Kl, Wkh, Wkl, kh, kl, 0};
  ga.p[2] = {Vh, Vl, Wvh, Wvl, vth, vtl, 2};
  gemm_qkv<<<dim3(8, 32, 3), blk, 0, stream>>>(ga);
  attn64q<<<dim3(1024), blk, 0, stream>>>(qh, ql, kh, kl, vth, vtl, bits, zh,
                                          zl);
  gemm_out<<<dim3(8, 32, 2), blk, 0, stream>>>(zh, zl, Woh, Wol, C0, C1);
  sumC<<<dim3(4096), blk, 0, stream>>>(C0, C1, out);
}